// Round 1
// baseline (1309.982 us; speedup 1.0000x reference)
//
#include <hip/hip_runtime.h>
#include <hip/hip_bf16.h>

#define SEQ 2048
#define DM 2048
#define NH 16
#define HD 128
#define FF 8192

typedef float f4v __attribute__((ext_vector_type(4)));
typedef short s8v __attribute__((ext_vector_type(8)));

__device__ __forceinline__ ushort f2bf(float f) {
  // round-to-nearest-even fp32 -> bf16 (bits)
  unsigned int x = __float_as_uint(f);
  unsigned int r = (x + 0x7FFFu + ((x >> 16) & 1u)) >> 16;
  return (ushort)r;
}

// ---------------- fp32 -> bf16 convert (optional exact gelu) ----------------
__global__ __launch_bounds__(256) void k_cvt(const float* __restrict__ in,
                                             ushort* __restrict__ out,
                                             int n4, int do_gelu) {
  int i = blockIdx.x * 256 + threadIdx.x;
  if (i >= n4) return;
  f4v v = reinterpret_cast<const f4v*>(in)[i];
  if (do_gelu) {
#pragma unroll
    for (int e = 0; e < 4; ++e)
      v[e] = 0.5f * v[e] * (1.0f + erff(v[e] * 0.70710678118654752f));
  }
  ushort4 u;
  u.x = f2bf(v[0]); u.y = f2bf(v[1]); u.z = f2bf(v[2]); u.w = f2bf(v[3]);
  reinterpret_cast<ushort4*>(out)[i] = u;
}

// ---------------- transpose + convert: W[K][N] fp32 -> Wt[N][K] bf16 --------
__global__ __launch_bounds__(256) void k_tr(const float* __restrict__ W,
                                            ushort* __restrict__ Wt,
                                            int K, int N) {
  __shared__ float tile[32][33];
  int tx = threadIdx.x & 31, ty = threadIdx.x >> 5;
  int n0 = blockIdx.x * 32, k0 = blockIdx.y * 32;
#pragma unroll
  for (int i = 0; i < 4; ++i)
    tile[ty + i * 8][tx] = W[(size_t)(k0 + ty + i * 8) * N + n0 + tx];
  __syncthreads();
#pragma unroll
  for (int i = 0; i < 4; ++i)
    Wt[(size_t)(n0 + ty + i * 8) * K + k0 + tx] = f2bf(tile[tx][ty + i * 8]);
}

// ---------------- bf16 MFMA GEMM: C[M][N] = A[M][K] * Bt[N][K]^T + bias -----
__global__ __launch_bounds__(256) void k_gemm(const ushort* __restrict__ A,
                                              const ushort* __restrict__ Bt,
                                              const float* __restrict__ bias,
                                              float* __restrict__ C,
                                              int M, int N, int K) {
  __shared__ ushort As[128][72];  // pad 64->72: 2-way (free) instead of 16-way
  __shared__ ushort Bs[128][72];
  int m0 = blockIdx.y * 128, n0 = blockIdx.x * 128;
  int t = threadIdx.x;
  int wave = t >> 6, lane = t & 63;
  int wm = (wave >> 1) * 64, wn = (wave & 1) * 64;
  int quad = lane >> 4, l16 = lane & 15;
  f4v acc[4][4] = {};
  int srow = t >> 3, scol = (t & 7) * 8;
  for (int k0 = 0; k0 < K; k0 += 64) {
#pragma unroll
    for (int p = 0; p < 4; ++p) {
      int r = srow + p * 32;
      *(uint4*)&As[r][scol] = *(const uint4*)&A[(size_t)(m0 + r) * K + k0 + scol];
      *(uint4*)&Bs[r][scol] = *(const uint4*)&Bt[(size_t)(n0 + r) * K + k0 + scol];
    }
    __syncthreads();
#pragma unroll
    for (int kk = 0; kk < 64; kk += 32) {
      s8v af[4], bf[4];
#pragma unroll
      for (int i = 0; i < 4; ++i)
        af[i] = *(const s8v*)&As[wm + i * 16 + l16][kk + quad * 8];
#pragma unroll
      for (int j = 0; j < 4; ++j)
        bf[j] = *(const s8v*)&Bs[wn + j * 16 + l16][kk + quad * 8];
#pragma unroll
      for (int i = 0; i < 4; ++i)
#pragma unroll
        for (int j = 0; j < 4; ++j)
          acc[i][j] = __builtin_amdgcn_mfma_f32_16x16x32_bf16(af[i], bf[j], acc[i][j], 0, 0, 0);
    }
    __syncthreads();
  }
  // C/D layout: col = lane&15, row = quad*4 + reg  (HW-verified mapping)
#pragma unroll
  for (int i = 0; i < 4; ++i) {
    int rbase = m0 + wm + i * 16 + quad * 4;
#pragma unroll
    for (int j = 0; j < 4; ++j) {
      int cidx = n0 + wn + j * 16 + l16;
      float b = bias[cidx];
#pragma unroll
      for (int r = 0; r < 4; ++r)
        C[(size_t)(rbase + r) * N + cidx] = acc[i][j][r] + b;
    }
  }
}

// ---------------- causal flash attention, fp32 VALU (correctness-first) -----
__global__ __launch_bounds__(256) void k_attn(const float* __restrict__ qkv,
                                              float* __restrict__ ctx) {
  __shared__ float Qs[32][132];
  __shared__ float Ks[32][132];
  __shared__ float Vs[32][132];
  __shared__ float Ps[32][33];
  __shared__ float redA[32][8];
  __shared__ float redB[32][8];
  __shared__ float m_s[32], l_s[32];
  const int qt = blockIdx.x, h = blockIdx.y;
  const int q0 = qt * 32;
  const int t = threadIdx.x;
  const int qr = t >> 3, c8 = t & 7;
  const float scale = 0.022097086912079608f;  // 1/sqrt(2048)

  // load Q tile (scaled)
#pragma unroll
  for (int p = 0; p < 4; ++p) {
    int id = t + p * 256;        // 0..1023
    int row = id >> 5, col = (id & 31) * 4;
    f4v v = *(const f4v*)&qkv[(size_t)(q0 + row) * (3 * DM) + h * HD + col];
    *(f4v*)&Qs[row][col] = v * scale;
  }
  if (t < 32) { m_s[t] = -1e30f; l_s[t] = 0.0f; }
  f4v o4[4] = {};

  for (int kt = 0; kt <= qt; ++kt) {
    int k0 = kt * 32;
    __syncthreads();  // protect LDS from previous iteration's readers
#pragma unroll
    for (int p = 0; p < 4; ++p) {
      int id = t + p * 256;
      int row = id >> 5, col = (id & 31) * 4;
      *(f4v*)&Ks[row][col] = *(const f4v*)&qkv[(size_t)(k0 + row) * (3 * DM) + DM + h * HD + col];
      *(f4v*)&Vs[row][col] = *(const f4v*)&qkv[(size_t)(k0 + row) * (3 * DM) + 2 * DM + h * HD + col];
    }
    __syncthreads();

    // S = Q K^T for rows this thread owns: j = c8 + jj*8
    float sv[4];
    {
      f4v a0 = {}, a1 = {}, a2 = {}, a3 = {};
#pragma unroll
      for (int c = 0; c < 32; ++c) {
        f4v qv = *(const f4v*)&Qs[qr][c * 4];
        a0 += qv * *(const f4v*)&Ks[c8][c * 4];
        a1 += qv * *(const f4v*)&Ks[c8 + 8][c * 4];
        a2 += qv * *(const f4v*)&Ks[c8 + 16][c * 4];
        a3 += qv * *(const f4v*)&Ks[c8 + 24][c * 4];
      }
      sv[0] = a0[0] + a0[1] + a0[2] + a0[3];
      sv[1] = a1[0] + a1[1] + a1[2] + a1[3];
      sv[2] = a2[0] + a2[1] + a2[2] + a2[3];
      sv[3] = a3[0] + a3[1] + a3[2] + a3[3];
    }
    int qg = q0 + qr;
    float lmax = -1e30f;
#pragma unroll
    for (int jj = 0; jj < 4; ++jj) {
      int kg = k0 + c8 + jj * 8;
      if (kg > qg) sv[jj] = -1e30f;
      lmax = fmaxf(lmax, sv[jj]);
    }
    redA[qr][c8] = lmax;
    __syncthreads();
    float tmax = redA[qr][0];
#pragma unroll
    for (int e = 1; e < 8; ++e) tmax = fmaxf(tmax, redA[qr][e]);
    float mold = m_s[qr];
    float mnew = fmaxf(mold, tmax);
    float alpha = __expf(mold - mnew);
    float psum = 0.0f;
#pragma unroll
    for (int jj = 0; jj < 4; ++jj) {
      float p = __expf(sv[jj] - mnew);
      Ps[qr][c8 + jj * 8] = p;
      psum += p;
    }
    redB[qr][c8] = psum;
    __syncthreads();
    float tsum = 0.0f;
#pragma unroll
    for (int e = 0; e < 8; ++e) tsum += redB[qr][e];
    float lnew = l_s[qr] * alpha + tsum;
    if (c8 == 0) { m_s[qr] = mnew; l_s[qr] = lnew; }
#pragma unroll
    for (int p4 = 0; p4 < 4; ++p4) o4[p4] *= alpha;
    for (int j = 0; j < 32; ++j) {
      float p = Ps[qr][j];
      const f4v* vr = (const f4v*)&Vs[j][0];
#pragma unroll
      for (int p4 = 0; p4 < 4; ++p4) o4[p4] += p * vr[c8 + p4 * 8];
    }
  }
  float rl = 1.0f / l_s[qr];
#pragma unroll
  for (int p4 = 0; p4 < 4; ++p4)
    *(f4v*)&ctx[(size_t)(q0 + qr) * DM + h * HD + (c8 + p4 * 8) * 4] = o4[p4] * rl;
}

// ---------------- layernorm(a + b): fp32 out + optional bf16 out ------------
__global__ __launch_bounds__(256) void k_ln(const float* __restrict__ A,
                                            const float* __restrict__ B,
                                            const float* __restrict__ g,
                                            const float* __restrict__ be,
                                            float* __restrict__ outf,
                                            ushort* __restrict__ outb) {
  int row = blockIdx.x;
  int t = threadIdx.x;
  const f4v* av = reinterpret_cast<const f4v*>(A + (size_t)row * DM);
  const f4v* bv = reinterpret_cast<const f4v*>(B + (size_t)row * DM);
  f4v x0 = av[t] + bv[t];
  f4v x1 = av[t + 256] + bv[t + 256];
  float s = x0[0] + x0[1] + x0[2] + x0[3] + x1[0] + x1[1] + x1[2] + x1[3];
  float q = x0[0]*x0[0] + x0[1]*x0[1] + x0[2]*x0[2] + x0[3]*x0[3]
          + x1[0]*x1[0] + x1[1]*x1[1] + x1[2]*x1[2] + x1[3]*x1[3];
#pragma unroll
  for (int off = 32; off; off >>= 1) {
    s += __shfl_down(s, off, 64);
    q += __shfl_down(q, off, 64);
  }
  __shared__ float rs[4], rq[4];
  if ((t & 63) == 0) { rs[t >> 6] = s; rq[t >> 6] = q; }
  __syncthreads();
  s = rs[0] + rs[1] + rs[2] + rs[3];
  q = rq[0] + rq[1] + rq[2] + rq[3];
  float mu = s * (1.0f / DM);
  float var = q * (1.0f / DM) - mu * mu;
  float rstd = rsqrtf(var + 1e-5f);
  const f4v* gv = reinterpret_cast<const f4v*>(g);
  const f4v* bev = reinterpret_cast<const f4v*>(be);
  f4v y0 = (x0 - mu) * rstd * gv[t] + bev[t];
  f4v y1 = (x1 - mu) * rstd * gv[t + 256] + bev[t + 256];
  reinterpret_cast<f4v*>(outf + (size_t)row * DM)[t] = y0;
  reinterpret_cast<f4v*>(outf + (size_t)row * DM)[t + 256] = y1;
  if (outb) {
    ushort4 u0, u1;
    u0.x = f2bf(y0[0]); u0.y = f2bf(y0[1]); u0.z = f2bf(y0[2]); u0.w = f2bf(y0[3]);
    u1.x = f2bf(y1[0]); u1.y = f2bf(y1[1]); u1.z = f2bf(y1[2]); u1.w = f2bf(y1[3]);
    reinterpret_cast<ushort4*>(outb + (size_t)row * DM)[t] = u0;
    reinterpret_cast<ushort4*>(outb + (size_t)row * DM)[t + 256] = u1;
  }
}

extern "C" void kernel_launch(void* const* d_in, const int* in_sizes, int n_in,
                              void* d_out, int out_size, void* d_ws, size_t ws_size,
                              hipStream_t stream) {
  const float* x     = (const float*)d_in[0];
  const float* C_w   = (const float*)d_in[1];
  const float* C_b   = (const float*)d_in[2];
  const float* lin_w = (const float*)d_in[3];
  const float* lin_b = (const float*)d_in[4];
  const float* ff1_w = (const float*)d_in[5];
  const float* ff1_b = (const float*)d_in[6];
  const float* ff2_w = (const float*)d_in[7];
  const float* ff2_b = (const float*)d_in[8];
  const float* ln1g  = (const float*)d_in[9];
  const float* ln1b  = (const float*)d_in[10];
  const float* ln2g  = (const float*)d_in[11];
  const float* ln2b  = (const float*)d_in[12];

  char* ws = (char*)d_ws;
  size_t off = 0;
  auto take = [&](size_t bytes) {
    char* p = ws + off;
    off += (bytes + 255) & ~(size_t)255;
    return p;
  };
  // total ws need ~193 MB
  ushort* Wt   = (ushort*)take((size_t)FF * DM * 2);   // transposed bf16 weight (reused)
  float*  bigf = (float*) take((size_t)SEQ * FF * 4);  // qkv fp32, later ff1out fp32
  ushort* xb   = (ushort*)take((size_t)SEQ * DM * 2);  // bf16 x, later bf16 h1
  float*  ctxf = (float*) take((size_t)SEQ * DM * 4);  // attn context fp32, later ff2out
  ushort* bigb = (ushort*)take((size_t)SEQ * FF * 2);  // bf16 ctx, later bf16 gelu(ff1)
  float*  attn = (float*) take((size_t)SEQ * DM * 4);  // proj output
  float*  h1   = (float*) take((size_t)SEQ * DM * 4);  // LN1 output fp32

  float* qkv = bigf;

  // x -> bf16
  k_cvt<<<SEQ * DM / 1024, 256, 0, stream>>>(x, xb, SEQ * DM / 4, 0);
  // qkv = x @ C_w + C_b
  k_tr<<<dim3(3 * DM / 32, DM / 32), 256, 0, stream>>>(C_w, Wt, DM, 3 * DM);
  k_gemm<<<dim3(3 * DM / 128, SEQ / 128), 256, 0, stream>>>(xb, Wt, C_b, qkv, SEQ, 3 * DM, DM);
  // causal attention -> ctxf
  k_attn<<<dim3(SEQ / 32, NH), 256, 0, stream>>>(qkv, ctxf);
  // attn = ctx @ lin_w + lin_b
  k_cvt<<<SEQ * DM / 1024, 256, 0, stream>>>(ctxf, bigb, SEQ * DM / 4, 0);
  k_tr<<<dim3(DM / 32, DM / 32), 256, 0, stream>>>(lin_w, Wt, DM, DM);
  k_gemm<<<dim3(DM / 128, SEQ / 128), 256, 0, stream>>>(bigb, Wt, lin_b, attn, SEQ, DM, DM);
  // h1 = LN(x + attn); h1 bf16 -> xb
  k_ln<<<SEQ, 256, 0, stream>>>(x, attn, ln1g, ln1b, h1, xb);
  // ff1 = h1 @ ff1_w + ff1_b
  k_tr<<<dim3(FF / 32, DM / 32), 256, 0, stream>>>(ff1_w, Wt, DM, FF);
  k_gemm<<<dim3(FF / 128, SEQ / 128), 256, 0, stream>>>(xb, Wt, ff1_b, bigf, SEQ, FF, DM);
  // gelu + bf16
  k_cvt<<<SEQ * FF / 1024, 256, 0, stream>>>(bigf, bigb, SEQ * FF / 4, 1);
  // ff2 = gelu(ff1) @ ff2_w + ff2_b
  k_tr<<<dim3(DM / 32, FF / 32), 256, 0, stream>>>(ff2_w, Wt, FF, DM);
  k_gemm<<<dim3(DM / 128, SEQ / 128), 256, 0, stream>>>(bigb, Wt, ff2_b, ctxf, SEQ, DM, FF);
  // out = LN(h1 + ff2)
  k_ln<<<SEQ, 256, 0, stream>>>(h1, ctxf, ln2g, ln2b, (float*)d_out, (ushort*)nullptr);
}

// Round 2
// 710.382 us; speedup vs baseline: 1.8441x; 1.8441x over previous
//
#include <hip/hip_runtime.h>
#include <hip/hip_bf16.h>

#define SEQ 2048
#define DM 2048
#define NH 16
#define HD 128
#define FF 8192

typedef float f4v __attribute__((ext_vector_type(4)));
typedef short s8v __attribute__((ext_vector_type(8)));

__device__ __forceinline__ ushort f2bf(float f) {
  unsigned int x = __float_as_uint(f);
  unsigned int r = (x + 0x7FFFu + ((x >> 16) & 1u)) >> 16;
  return (ushort)r;
}

// ---------------- fp32 -> bf16 convert ----------------
__global__ __launch_bounds__(256) void k_cvt(const float* __restrict__ in,
                                             ushort* __restrict__ out, int n4) {
  int i = blockIdx.x * 256 + threadIdx.x;
  if (i >= n4) return;
  f4v v = reinterpret_cast<const f4v*>(in)[i];
  ushort4 u;
  u.x = f2bf(v[0]); u.y = f2bf(v[1]); u.z = f2bf(v[2]); u.w = f2bf(v[3]);
  reinterpret_cast<ushort4*>(out)[i] = u;
}

// ---------------- transpose + convert: W[K][N] fp32 -> Wt[N][K] bf16 --------
__global__ __launch_bounds__(256) void k_tr(const float* __restrict__ W,
                                            ushort* __restrict__ Wt,
                                            int K, int N) {
  __shared__ float tile[32][33];
  int tx = threadIdx.x & 31, ty = threadIdx.x >> 5;
  int n0 = blockIdx.x * 32, k0 = blockIdx.y * 32;
#pragma unroll
  for (int i = 0; i < 4; ++i)
    tile[ty + i * 8][tx] = W[(size_t)(k0 + ty + i * 8) * N + n0 + tx];
  __syncthreads();
#pragma unroll
  for (int i = 0; i < 4; ++i)
    Wt[(size_t)(n0 + ty + i * 8) * K + k0 + tx] = f2bf(tile[tx][ty + i * 8]);
}

// ---------------- bf16 MFMA GEMM: C = A[M][K] * Bt[N][K]^T + bias -----------
// Cf: fp32 out (may be null). Cb: bf16 out (may be null). gelu applied if flag.
__global__ __launch_bounds__(256) void k_gemm(const ushort* __restrict__ A,
                                              const ushort* __restrict__ Bt,
                                              const float* __restrict__ bias,
                                              float* __restrict__ Cf,
                                              ushort* __restrict__ Cb,
                                              int M, int N, int K, int gelu) {
  __shared__ ushort As[128][72];
  __shared__ ushort Bs[128][72];
  int m0 = blockIdx.y * 128, n0 = blockIdx.x * 128;
  int t = threadIdx.x;
  int wave = t >> 6, lane = t & 63;
  int wm = (wave >> 1) * 64, wn = (wave & 1) * 64;
  int quad = lane >> 4, l16 = lane & 15;
  f4v acc[4][4] = {};
  int srow = t >> 3, scol = (t & 7) * 8;
  for (int k0 = 0; k0 < K; k0 += 64) {
#pragma unroll
    for (int p = 0; p < 4; ++p) {
      int r = srow + p * 32;
      *(uint4*)&As[r][scol] = *(const uint4*)&A[(size_t)(m0 + r) * K + k0 + scol];
      *(uint4*)&Bs[r][scol] = *(const uint4*)&Bt[(size_t)(n0 + r) * K + k0 + scol];
    }
    __syncthreads();
#pragma unroll
    for (int kk = 0; kk < 64; kk += 32) {
      s8v af[4], bf[4];
#pragma unroll
      for (int i = 0; i < 4; ++i)
        af[i] = *(const s8v*)&As[wm + i * 16 + l16][kk + quad * 8];
#pragma unroll
      for (int j = 0; j < 4; ++j)
        bf[j] = *(const s8v*)&Bs[wn + j * 16 + l16][kk + quad * 8];
#pragma unroll
      for (int i = 0; i < 4; ++i)
#pragma unroll
        for (int j = 0; j < 4; ++j)
          acc[i][j] = __builtin_amdgcn_mfma_f32_16x16x32_bf16(af[i], bf[j], acc[i][j], 0, 0, 0);
    }
    __syncthreads();
  }
#pragma unroll
  for (int i = 0; i < 4; ++i) {
    int rbase = m0 + wm + i * 16 + quad * 4;
#pragma unroll
    for (int j = 0; j < 4; ++j) {
      int cidx = n0 + wn + j * 16 + l16;
      float b = bias[cidx];
#pragma unroll
      for (int r = 0; r < 4; ++r) {
        float v = acc[i][j][r] + b;
        if (gelu) v = 0.5f * v * (1.0f + erff(v * 0.70710678118654752f));
        if (Cf) Cf[(size_t)(rbase + r) * N + cidx] = v;
        if (Cb) Cb[(size_t)(rbase + r) * N + cidx] = f2bf(v);
      }
    }
  }
}

// ---------------- MFMA flash attention (bf16 in/out, fp32 softmax) ----------
// Block: 4 waves, one head, 64 Q rows (wave w owns rows 16w..16w+16).
// K tile = 64. Ks[s][hd] B-layout for QK; Vt[hd][s] B-layout for PV.
__global__ __launch_bounds__(256) void k_attn_mfma(const ushort* __restrict__ qkv,
                                                   ushort* __restrict__ ctx) {
  __shared__ ushort Ks[64][136];   // stride 136 shorts = 272B (16B-aligned, 2-way banks)
  __shared__ ushort Vt[128][72];   // stride 72 shorts = 144B (16B-aligned, 2-way banks)
  __shared__ ushort Ps[4][16][72]; // per-wave P tile, A-layout source
  const int idx = blockIdx.x;
  const int h = idx & (NH - 1);
  const int qt = (SEQ / 64 - 1) - (idx >> 4);   // longest blocks first
  const int q0 = qt * 64;
  const int t = threadIdx.x;
  const int wave = t >> 6, lane = t & 63;
  const int quad = lane >> 4, l16 = lane & 15;
  const float scale = 0.022097086912079608f;    // 1/sqrt(2048)

  // Q fragments (A-layout), resident in registers for the whole block
  s8v aq[4];
  {
    const ushort* qp = qkv + (size_t)(q0 + 16 * wave + l16) * (3 * DM) + h * HD + quad * 8;
#pragma unroll
    for (int ks = 0; ks < 4; ++ks)
      aq[ks] = *(const s8v*)(qp + ks * 32);
  }
  f4v acc_o[8] = {};
  float m_r[4], l_r[4];
#pragma unroll
  for (int r = 0; r < 4; ++r) { m_r[r] = -1e30f; l_r[r] = 0.0f; }

  for (int kt = 0; kt <= qt; ++kt) {
    const int k0 = kt * 64;
    __syncthreads();
    // ---- stage K tile: Ks[s][d], 64x128 bf16
    {
      const ushort* kp = qkv + (size_t)k0 * (3 * DM) + DM + h * HD;
#pragma unroll
      for (int i = 0; i < 4; ++i) {
        int ch = t + i * 256;             // 0..1023
        int row = ch >> 4, c8 = (ch & 15) * 8;
        *(s8v*)&Ks[row][c8] = *(const s8v*)(kp + (size_t)row * (3 * DM) + c8);
      }
      // ---- stage V transposed: Vt[d][s]; lane<->d keeps LDS writes conflict-light
      const ushort* vp = qkv + (size_t)k0 * (3 * DM) + 2 * DM + h * HD;
#pragma unroll
      for (int i = 0; i < 4; ++i) {
        int id = t + i * 256;             // 0..1023
        int d = id & 127, sg = id >> 7;   // sg 0..7, covers s = 8sg..8sg+7
        ushort e0 = vp[(size_t)(sg * 8 + 0) * (3 * DM) + d];
        ushort e1 = vp[(size_t)(sg * 8 + 1) * (3 * DM) + d];
        ushort e2 = vp[(size_t)(sg * 8 + 2) * (3 * DM) + d];
        ushort e3 = vp[(size_t)(sg * 8 + 3) * (3 * DM) + d];
        ushort e4 = vp[(size_t)(sg * 8 + 4) * (3 * DM) + d];
        ushort e5 = vp[(size_t)(sg * 8 + 5) * (3 * DM) + d];
        ushort e6 = vp[(size_t)(sg * 8 + 6) * (3 * DM) + d];
        ushort e7 = vp[(size_t)(sg * 8 + 7) * (3 * DM) + d];
        uint4 pk;
        pk.x = (uint)e0 | ((uint)e1 << 16);
        pk.y = (uint)e2 | ((uint)e3 << 16);
        pk.z = (uint)e4 | ((uint)e5 << 16);
        pk.w = (uint)e6 | ((uint)e7 << 16);
        *(uint4*)&Vt[d][sg * 8] = pk;
      }
    }
    __syncthreads();

    // ---- S = scale * Q K^T   (each wave: its 16 rows x 64 cols)
    f4v sacc[4] = {};
#pragma unroll
    for (int ks = 0; ks < 4; ++ks) {
      s8v bk[4];
#pragma unroll
      for (int j = 0; j < 4; ++j)
        bk[j] = *(const s8v*)&Ks[j * 16 + l16][ks * 32 + quad * 8];
#pragma unroll
      for (int j = 0; j < 4; ++j)
        sacc[j] = __builtin_amdgcn_mfma_f32_16x16x32_bf16(aq[ks], bk[j], sacc[j], 0, 0, 0);
    }
    // scale + causal mask (diag tile only)
    if (kt == qt) {
#pragma unroll
      for (int j = 0; j < 4; ++j)
#pragma unroll
        for (int r = 0; r < 4; ++r) {
          int lrow = 16 * wave + quad * 4 + r;
          int lcol = j * 16 + l16;
          sacc[j][r] = (lcol > lrow) ? -1e30f : sacc[j][r] * scale;
        }
    } else {
#pragma unroll
      for (int j = 0; j < 4; ++j)
#pragma unroll
        for (int r = 0; r < 4; ++r) sacc[j][r] *= scale;
    }
    // ---- online softmax (rows are wave-local; reduce over 16 lanes)
    float alpha[4];
#pragma unroll
    for (int r = 0; r < 4; ++r) {
      float mx = fmaxf(fmaxf(sacc[0][r], sacc[1][r]), fmaxf(sacc[2][r], sacc[3][r]));
      mx = fmaxf(mx, __shfl_xor(mx, 1));
      mx = fmaxf(mx, __shfl_xor(mx, 2));
      mx = fmaxf(mx, __shfl_xor(mx, 4));
      mx = fmaxf(mx, __shfl_xor(mx, 8));
      float mn = fmaxf(m_r[r], mx);
      alpha[r] = __expf(m_r[r] - mn);
      m_r[r] = mn;
      float ps = 0.0f;
#pragma unroll
      for (int j = 0; j < 4; ++j) {
        float p = __expf(sacc[j][r] - mn);
        sacc[j][r] = p;
        ps += p;
      }
      ps += __shfl_xor(ps, 1);
      ps += __shfl_xor(ps, 2);
      ps += __shfl_xor(ps, 4);
      ps += __shfl_xor(ps, 8);
      l_r[r] = l_r[r] * alpha[r] + ps;
    }
    // ---- P (C-layout) -> LDS -> A-layout
#pragma unroll
    for (int j = 0; j < 4; ++j)
#pragma unroll
      for (int r = 0; r < 4; ++r)
        Ps[wave][quad * 4 + r][j * 16 + l16] = f2bf(sacc[j][r]);
    // rescale O by alpha (row r lives in reg r of each accumulator)
#pragma unroll
    for (int nd = 0; nd < 8; ++nd)
#pragma unroll
      for (int r = 0; r < 4; ++r) acc_o[nd][r] *= alpha[r];
    // ---- O += P V
#pragma unroll
    for (int ks2 = 0; ks2 < 2; ++ks2) {
      s8v ap = *(const s8v*)&Ps[wave][l16][ks2 * 32 + quad * 8];
#pragma unroll
      for (int nd = 0; nd < 8; ++nd) {
        s8v bv = *(const s8v*)&Vt[nd * 16 + l16][ks2 * 32 + quad * 8];
        acc_o[nd] = __builtin_amdgcn_mfma_f32_16x16x32_bf16(ap, bv, acc_o[nd], 0, 0, 0);
      }
    }
  }
  // ---- epilogue: O / l -> bf16 ctx
  float rl[4];
#pragma unroll
  for (int r = 0; r < 4; ++r) rl[r] = 1.0f / l_r[r];
#pragma unroll
  for (int nd = 0; nd < 8; ++nd) {
    int col = h * HD + nd * 16 + l16;
#pragma unroll
    for (int r = 0; r < 4; ++r) {
      int row = q0 + 16 * wave + quad * 4 + r;
      ctx[(size_t)row * DM + col] = f2bf(acc_o[nd][r] * rl[r]);
    }
  }
}

// ---------------- layernorm(a + b): fp32 out + optional bf16 out ------------
__global__ __launch_bounds__(256) void k_ln(const float* __restrict__ A,
                                            const float* __restrict__ B,
                                            const float* __restrict__ g,
                                            const float* __restrict__ be,
                                            float* __restrict__ outf,
                                            ushort* __restrict__ outb) {
  int row = blockIdx.x;
  int t = threadIdx.x;
  const f4v* av = reinterpret_cast<const f4v*>(A + (size_t)row * DM);
  const f4v* bv = reinterpret_cast<const f4v*>(B + (size_t)row * DM);
  f4v x0 = av[t] + bv[t];
  f4v x1 = av[t + 256] + bv[t + 256];
  float s = x0[0] + x0[1] + x0[2] + x0[3] + x1[0] + x1[1] + x1[2] + x1[3];
  float q = x0[0]*x0[0] + x0[1]*x0[1] + x0[2]*x0[2] + x0[3]*x0[3]
          + x1[0]*x1[0] + x1[1]*x1[1] + x1[2]*x1[2] + x1[3]*x1[3];
#pragma unroll
  for (int off = 32; off; off >>= 1) {
    s += __shfl_down(s, off, 64);
    q += __shfl_down(q, off, 64);
  }
  __shared__ float rs[4], rq[4];
  if ((t & 63) == 0) { rs[t >> 6] = s; rq[t >> 6] = q; }
  __syncthreads();
  s = rs[0] + rs[1] + rs[2] + rs[3];
  q = rq[0] + rq[1] + rq[2] + rq[3];
  float mu = s * (1.0f / DM);
  float var = q * (1.0f / DM) - mu * mu;
  float rstd = rsqrtf(var + 1e-5f);
  const f4v* gv = reinterpret_cast<const f4v*>(g);
  const f4v* bev = reinterpret_cast<const f4v*>(be);
  f4v y0 = (x0 - mu) * rstd * gv[t] + bev[t];
  f4v y1 = (x1 - mu) * rstd * gv[t + 256] + bev[t + 256];
  reinterpret_cast<f4v*>(outf + (size_t)row * DM)[t] = y0;
  reinterpret_cast<f4v*>(outf + (size_t)row * DM)[t + 256] = y1;
  if (outb) {
    ushort4 u0, u1;
    u0.x = f2bf(y0[0]); u0.y = f2bf(y0[1]); u0.z = f2bf(y0[2]); u0.w = f2bf(y0[3]);
    u1.x = f2bf(y1[0]); u1.y = f2bf(y1[1]); u1.z = f2bf(y1[2]); u1.w = f2bf(y1[3]);
    reinterpret_cast<ushort4*>(outb + (size_t)row * DM)[t] = u0;
    reinterpret_cast<ushort4*>(outb + (size_t)row * DM)[t + 256] = u1;
  }
}

extern "C" void kernel_launch(void* const* d_in, const int* in_sizes, int n_in,
                              void* d_out, int out_size, void* d_ws, size_t ws_size,
                              hipStream_t stream) {
  const float* x     = (const float*)d_in[0];
  const float* C_w   = (const float*)d_in[1];
  const float* C_b   = (const float*)d_in[2];
  const float* lin_w = (const float*)d_in[3];
  const float* lin_b = (const float*)d_in[4];
  const float* ff1_w = (const float*)d_in[5];
  const float* ff1_b = (const float*)d_in[6];
  const float* ff2_w = (const float*)d_in[7];
  const float* ff2_b = (const float*)d_in[8];
  const float* ln1g  = (const float*)d_in[9];
  const float* ln1b  = (const float*)d_in[10];
  const float* ln2g  = (const float*)d_in[11];
  const float* ln2b  = (const float*)d_in[12];

  char* ws = (char*)d_ws;
  size_t off = 0;
  auto take = [&](size_t bytes) {
    char* p = ws + off;
    off += (bytes + 255) & ~(size_t)255;
    return p;
  };
  ushort* Wt   = (ushort*)take((size_t)FF * DM * 2);    // transposed bf16 weight (reused)
  ushort* qkvb = (ushort*)take((size_t)SEQ * 3 * DM * 2);
  ushort* xb   = (ushort*)take((size_t)SEQ * DM * 2);   // bf16 x, later bf16 h1
  ushort* ctxb = (ushort*)take((size_t)SEQ * DM * 2);   // bf16 attention context
  ushort* bigb = (ushort*)take((size_t)SEQ * FF * 2);   // bf16 gelu(ff1)
  float*  attn = (float*) take((size_t)SEQ * DM * 4);   // proj output fp32
  float*  h1   = (float*) take((size_t)SEQ * DM * 4);   // LN1 output fp32
  float*  ff2o = (float*) take((size_t)SEQ * DM * 4);   // ff2 output fp32

  // x -> bf16
  k_cvt<<<SEQ * DM / 1024, 256, 0, stream>>>(x, xb, SEQ * DM / 4);
  // qkv = x @ C_w + C_b  (bf16 out)
  k_tr<<<dim3(3 * DM / 32, DM / 32), 256, 0, stream>>>(C_w, Wt, DM, 3 * DM);
  k_gemm<<<dim3(3 * DM / 128, SEQ / 128), 256, 0, stream>>>(xb, Wt, C_b, nullptr, qkvb, SEQ, 3 * DM, DM, 0);
  // causal MFMA flash attention -> ctxb (bf16)
  k_attn_mfma<<<dim3((SEQ / 64) * NH), 256, 0, stream>>>(qkvb, ctxb);
  // attn = ctx @ lin_w + lin_b  (fp32 out)
  k_tr<<<dim3(DM / 32, DM / 32), 256, 0, stream>>>(lin_w, Wt, DM, DM);
  k_gemm<<<dim3(DM / 128, SEQ / 128), 256, 0, stream>>>(ctxb, Wt, lin_b, attn, nullptr, SEQ, DM, DM, 0);
  // h1 = LN(x + attn); bf16 copy -> xb
  k_ln<<<SEQ, 256, 0, stream>>>(x, attn, ln1g, ln1b, h1, xb);
  // ff1 = gelu(h1 @ ff1_w + ff1_b)  (bf16 out, fused gelu)
  k_tr<<<dim3(FF / 32, DM / 32), 256, 0, stream>>>(ff1_w, Wt, DM, FF);
  k_gemm<<<dim3(FF / 128, SEQ / 128), 256, 0, stream>>>(xb, Wt, ff1_b, nullptr, bigb, SEQ, FF, DM, 1);
  // ff2 = gelu(ff1) @ ff2_w + ff2_b  (fp32 out)
  k_tr<<<dim3(DM / 32, FF / 32), 256, 0, stream>>>(ff2_w, Wt, FF, DM);
  k_gemm<<<dim3(DM / 128, SEQ / 128), 256, 0, stream>>>(bigb, Wt, ff2_b, ff2o, nullptr, SEQ, DM, FF, 0);
  // out = LN(h1 + ff2)
  k_ln<<<SEQ, 256, 0, stream>>>(h1, ff2o, ln2g, ln2b, (float*)d_out, (ushort*)nullptr);
}